// Round 1
// baseline (348.427 us; speedup 1.0000x reference)
//
#include <hip/hip_runtime.h>
#include <math.h>

#define GRAPHS 8192
#define M 64
#define KNBR 32
#define NK (GRAPHS * M * KNBR)   // 16,777,216 edges

// One block per graph (256 threads = 4 waves). Each wave handles 16 nodes.
// Per node: 64 lanes compute gram-trick sq-dist to candidate j=lane, pack
// (sq_bits & ~63)|lane into a u32 key, bitonic-sort 64 lanes ascending.
// Lanes 0..31 hold the K nearest in ascending order (top_k-stable via index
// tie-break in the low bits). Epilogue recomputes exact gram sq for the
// `valid` comparison and the diff-based sqrt for edge_weight.
__global__ __launch_bounds__(256) void radius_graph_kernel(
    const float* __restrict__ pos, float* __restrict__ out) {
#pragma clang fp contract(off)
  __shared__ float sx[M], sy[M], sz[M], sn2[M];

  const int g    = blockIdx.x;
  const int tid  = threadIdx.x;
  const int lane = tid & 63;
  const int wave = tid >> 6;
  const int base = g * M;   // first global node of this graph

  if (tid < M) {
    float x = pos[(size_t)(base + tid) * 3 + 0];
    float y = pos[(size_t)(base + tid) * 3 + 1];
    float z = pos[(size_t)(base + tid) * 3 + 2];
    sx[tid] = x; sy[tid] = y; sz[tid] = z;
    sn2[tid] = (x * x + y * y) + z * z;   // plain ops, matches np sum order
  }
  __syncthreads();

  // candidate j = lane, hoisted out of the node loop
  const float xj = sx[lane], yj = sy[lane], zj = sz[lane], n2j = sn2[lane];

  for (int t = 0; t < 16; ++t) {
    const int i = wave * 16 + t;
    const float xi = sx[i], yi = sy[i], zi = sz[i], n2i = sn2[i];

    // gram-trick sq distance; dot as FMA chain (XLA-dot guess), rest plain
    float gd = __builtin_fmaf(zi, zj, __builtin_fmaf(yi, yj, xi * xj));
    float sq = fmaxf((n2i + n2j) - 2.0f * gd, 0.0f);

    unsigned kb  = __float_as_uint(sq);
    unsigned key = (lane == i) ? (0xFFFFFFC0u | (unsigned)lane)
                               : ((kb & 0xFFFFFFC0u) | (unsigned)lane);

    // 64-lane bitonic sort, ascending (keys unique: low 6 bits = lane)
    #pragma unroll
    for (int kk = 2; kk <= 64; kk <<= 1) {
      #pragma unroll
      for (int j = kk >> 1; j > 0; j >>= 1) {
        unsigned other = __shfl_xor(key, j, 64);
        bool asc = ((lane & kk) == 0);
        bool low = ((lane & j) == 0);
        unsigned mn = key < other ? key : other;
        unsigned mx = key < other ? other : key;
        key = (asc == low) ? mn : mx;
      }
    }

    if (lane < KNBR) {
      int nb = (int)(key & 63u);
      // exact gram sq for the valid decision (same expression as above)
      float xn = sx[nb], yn = sy[nb], zn = sz[nb];
      float gde = __builtin_fmaf(zi, zn, __builtin_fmaf(yi, yn, xi * xn));
      float sqe = fmaxf((n2i + sn2[nb]) - 2.0f * gde, 0.0f);
      bool valid = (sqe <= 0.25f);

      int tgt = base + i;
      int src = valid ? (base + nb) : tgt;

      // edge_weight from the diff formulation, np sum order
      float dx = xn - xi, dy = yn - yi, dz = zn - zi;
      float w  = valid ? sqrtf((dx * dx + dy * dy) + dz * dz) : 0.0f;

      size_t e = (size_t)tgt * KNBR + (size_t)lane;
      out[e]                    = (float)src;      // edge_index row
      out[(size_t)NK + e]       = (float)tgt;      // edge_index col
      out[2 * (size_t)NK + e]   = w;               // edge_weight
      out[3 * (size_t)NK + e]   = valid ? 1.0f : 0.0f;  // valid
    }
  }
}

extern "C" void kernel_launch(void* const* d_in, const int* in_sizes, int n_in,
                              void* d_out, int out_size, void* d_ws, size_t ws_size,
                              hipStream_t stream) {
  const float* pos = (const float*)d_in[0];
  // d_in[1] (batch) unused: graphs are equal-size (M=64), derived from index.
  float* out = (float*)d_out;
  radius_graph_kernel<<<GRAPHS, 256, 0, stream>>>(pos, out);
}